// Round 5
// baseline (496.834 us; speedup 1.0000x reference)
//
#include <hip/hip_runtime.h>
#include <hip/hip_bf16.h>

#define BATCH   16384
#define IN_F    1024
#define OUT_F   1024
#define KCOLS   11
#define KPL     12          // 11 basis planes + 1 x-plane (for W)
#define KP      (KPL*IN_F)  // 12288
#define KHALF   (KP/2)      // 6144 per split-K block
#define NTKH    (KHALF/64)  // 96 K-tiles of 64 per half
#define NITH    (NTKH/2)    // 48 main-loop iterations (2 K-tiles each)
#define LN_EPS  1e-5f

typedef __attribute__((ext_vector_type(8))) short short8;
typedef __attribute__((ext_vector_type(4))) float f32x4;
typedef __attribute__((ext_vector_type(16))) float f32x16;

static __device__ __forceinline__ unsigned short f2bf(float f) {
  __hip_bfloat16 h = __float2bfloat16(f);
  return *reinterpret_cast<unsigned short*>(&h);
}

// Cox-de Boor, faithful to the reference's in-place variant.
// All denominators are compile-time constants -> multiply by folded reciprocal.
__device__ __forceinline__ void bspline_basis(float x, float bas[KCOLS]) {
  const float s = 1.0f / 11.0f;
  float kn[12];
#pragma unroll
  for (int j = 0; j < 12; ++j) kn[j] = (float)j * s;
  kn[11] = 1.0f;
#pragma unroll
  for (int j = 0; j < 11; ++j)
    bas[j] = (x >= kn[j] && x < kn[j + 1]) ? 1.0f : 0.0f;
#pragma unroll
  for (int d = 1; d <= 3; ++d) {
#pragma unroll
    for (int j = 0; j < 11 - d; ++j) {
      const float r1 = 1.0f / (kn[j + d] - kn[j]);
      const float r2 = 1.0f / (kn[j + d + 1] - kn[j + 1]);
      float a = (x - kn[j]) * r1;
      float c = (kn[j + d + 1] - x) * r2;
      bas[j] = a * bas[j] + c * bas[j + 1];
    }
  }
}

// A[localRow][k*1024 + i] (bf16): 11 basis planes + x plane.
__global__ __launch_bounds__(256) void featgen(const float* __restrict__ X,
                                               unsigned short* __restrict__ A,
                                               int row0) {
  const int brow = blockIdx.x;
  const int i0 = threadIdx.x * 4;
  const float4 xv = *reinterpret_cast<const float4*>(X + (size_t)(row0 + brow) * IN_F + i0);
  float xs[4] = {xv.x, xv.y, xv.z, xv.w};
  float bas[4][KCOLS];
#pragma unroll
  for (int t = 0; t < 4; ++t) bspline_basis(xs[t], bas[t]);
  unsigned short* outp = A + (size_t)brow * KP + i0;
#pragma unroll
  for (int k = 0; k < KCOLS; ++k) {
    ushort4 u;
    u.x = f2bf(bas[0][k]); u.y = f2bf(bas[1][k]);
    u.z = f2bf(bas[2][k]); u.w = f2bf(bas[3][k]);
    *reinterpret_cast<ushort4*>(outp + (size_t)k * IN_F) = u;
  }
  ushort4 u;
  u.x = f2bf(xs[0]); u.y = f2bf(xs[1]); u.z = f2bf(xs[2]); u.w = f2bf(xs[3]);
  *reinterpret_cast<ushort4*>(outp + (size_t)KCOLS * IN_F) = u;
}

// Bmat[o][k*1024 + i] (bf16): cp planes + W plane.
__global__ __launch_bounds__(256) void bgen(const float* __restrict__ CP,
                                            const float* __restrict__ W,
                                            unsigned short* __restrict__ Bm) {
  const int o = blockIdx.x;
  const int i0 = threadIdx.x * 4;
  unsigned short* outp = Bm + (size_t)o * KP + i0;
#pragma unroll
  for (int k = 0; k < KCOLS; ++k) {
    ushort4 u;
    u.x = f2bf(CP[((size_t)o * IN_F + i0 + 0) * KCOLS + k]);
    u.y = f2bf(CP[((size_t)o * IN_F + i0 + 1) * KCOLS + k]);
    u.z = f2bf(CP[((size_t)o * IN_F + i0 + 2) * KCOLS + k]);
    u.w = f2bf(CP[((size_t)o * IN_F + i0 + 3) * KCOLS + k]);
    *reinterpret_cast<ushort4*>(outp + (size_t)k * IN_F) = u;
  }
  ushort4 u;
  u.x = f2bf(W[(size_t)o * IN_F + i0 + 0]);
  u.y = f2bf(W[(size_t)o * IN_F + i0 + 1]);
  u.z = f2bf(W[(size_t)o * IN_F + i0 + 2]);
  u.w = f2bf(W[(size_t)o * IN_F + i0 + 3]);
  *reinterpret_cast<ushort4*>(outp + (size_t)KCOLS * IN_F) = u;
}

// ---------------- 256x256 8-phase split-K GEMM (32x32x16 MFMA) ----------------
// ks=0 blocks -> Cc, ks=1 blocks -> Cp. Grid = nbm*8; 8192 rows -> 256 WGs.
// 512 thr = 8 waves (2M x 4N); per wave 128x64 out = 4 Mtiles x 2 Ntiles of 32x32.
// BK=64; LDS 128 KiB double-buffered; staging identical to r4 (shape-agnostic).

#define BAR()    __builtin_amdgcn_s_barrier()
#define SCHED0() __builtin_amdgcn_sched_barrier(0)
#define WAITV(N) asm volatile("s_waitcnt vmcnt(" #N ")" ::: "memory")

__global__ __launch_bounds__(512, 2) void gemm8p(const unsigned short* __restrict__ A,
                                                 const unsigned short* __restrict__ Bm,
                                                 float* __restrict__ Cc,
                                                 float* __restrict__ Cp, int nbm) {
  __shared__ unsigned short lds[2][2][2][128 * 64];  // [buf][A=0/B=1][half][...]
  const int tid  = (int)threadIdx.x;
  const int lane = tid & 63;
  const int w    = tid >> 6;
  const int wm   = w >> 2;       // 0..1
  const int wn   = w & 3;        // 0..3

  // XCD-aware bijective swizzle; per-XCD chunk = {4 bm} x {2 ks} x {4 bn}.
  const int nwg = nbm * 8;
  const int cpx = nwg >> 3;
  const int bid = (int)blockIdx.x;
  const int swz = (bid & 7) * cpx + (bid >> 3);
  const int bn = swz & 3;
  const int ks = (swz >> 2) & 1;
  const int bm = swz >> 3;
  const size_t koff = (size_t)ks * KHALF;
  float* __restrict__ C = ks ? Cp : Cc;

  // staging: one issue = 512 thr x 16 B = 64 rows x 64 cols.
  // Linear LDS dest; source col carries the inverse swizzle c ^ (row&7).
  const int srow = (w << 3) + (lane >> 3);            // 0..63 within one issue
  const int scol = ((lane & 7) ^ (lane >> 3)) << 3;   // element col, swizzled
  const unsigned short* aB = A  + (size_t)(bm * 256 + srow) * KP + koff + scol;
  const unsigned short* bB = Bm + (size_t)(bn * 256 + srow) * KP + koff + scol;

#define STAGE(T, AB, H, BUF)                                                          \
  do {                                                                                \
    if ((T) < NTKH) {                                                                 \
      const unsigned short* g_ = ((AB) ? bB : aB) + (size_t)(H) * 128 * KP + (size_t)(T) * 64; \
      unsigned short* l_ = &lds[BUF][AB][H][w * 512];                                 \
      __builtin_amdgcn_global_load_lds((const __attribute__((address_space(1))) void*)g_,       \
                                       (__attribute__((address_space(3))) void*)l_, 16, 0, 0);  \
      __builtin_amdgcn_global_load_lds((const __attribute__((address_space(1))) void*)(g_ + (size_t)64 * KP), \
                                       (__attribute__((address_space(3))) void*)(l_ + 4096), 16, 0, 0); \
    }                                                                                 \
  } while (0)

  // fragment reads (ds_read_b128, swizzled col). Row bases are ==0 mod 8, so
  // row&7 == lane&7 and the swizzled chunk is (kstep*2 + (lane>>5)) ^ (lane&7).
  const int r31 = lane & 31;
  const int kl  = lane >> 5;        // 0/1: k-half within a 16-wide kstep
  const int s7b = lane & 7;
  int cole[4];
#pragma unroll
  for (int ks_ = 0; ks_ < 4; ++ks_) cole[ks_] = (((ks_ << 1) | kl) ^ s7b) << 3;

  const unsigned short* aH[2] = {&lds[0][0][wm][0], &lds[1][0][wm][0]};
  const unsigned short* bH[2] = {&lds[0][1][wn >> 1][0], &lds[1][1][wn >> 1][0]};
  const int brow0 = (wn & 1) * 64;

  short8 aF[2][4], bF0[4], bF1[4];
  f32x16 acc[4][2] = {};

#define LOADA32(MB, BUF)                                                       \
  do {                                                                         \
    _Pragma("unroll") for (int m_ = 0; m_ < 2; ++m_) {                         \
      const unsigned short* p_ = aH[BUF] + (((MB) + m_) * 32 + r31) * 64;      \
      _Pragma("unroll") for (int ks_ = 0; ks_ < 4; ++ks_)                      \
        aF[m_][ks_] = *reinterpret_cast<const short8*>(p_ + cole[ks_]);        \
    }                                                                          \
  } while (0)

#define LOADB32(DST, NT, BUF)                                                  \
  do {                                                                         \
    const unsigned short* p_ = bH[BUF] + (brow0 + (NT) * 32 + r31) * 64;       \
    _Pragma("unroll") for (int ks_ = 0; ks_ < 4; ++ks_)                        \
      DST[ks_] = *reinterpret_cast<const short8*>(p_ + cole[ks_]);             \
  } while (0)

#define MFMAQ32(MB, NT, BF)                                                    \
  do {                                                                         \
    __builtin_amdgcn_s_setprio(1);                                             \
    _Pragma("unroll") for (int ks_ = 0; ks_ < 4; ++ks_)                        \
    _Pragma("unroll") for (int m_ = 0; m_ < 2; ++m_)                           \
      acc[(MB) + m_][NT] = __builtin_amdgcn_mfma_f32_32x32x16_bf16(            \
          aF[m_][ks_], BF[ks_], acc[(MB) + m_][NT], 0, 0, 0);                  \
    __builtin_amdgcn_s_setprio(0);                                             \
  } while (0)

  // prologue: tile0 (B0,B1,A0,A1) + tile1 (B0,B1); drain to 4 outstanding.
  STAGE(0, 1, 0, 0); STAGE(0, 1, 1, 0);
  STAGE(0, 0, 0, 0); STAGE(0, 0, 1, 0);
  STAGE(1, 1, 0, 1); STAGE(1, 1, 1, 1);
  WAITV(4);
  BAR();

#pragma unroll 1
  for (int j = 0; j < NITH; ++j) {
    const int tA = 2 * j + 1, tB2 = 2 * j + 2, tB3 = 2 * j + 3;
    // P1: Mt01 x Nt0 of tile 2j (buf0); stage A-half0 of 2j+1 -> buf1
    LOADA32(0, 0); LOADB32(bF0, 0, 0);
    STAGE(tA, 0, 0, 1);
    BAR();
    MFMAQ32(0, 0, bF0);
    SCHED0(); BAR();
    // P2: Mt01 x Nt1; stage A-half1 of 2j+1
    LOADB32(bF1, 1, 0);
    STAGE(tA, 0, 1, 1);
    BAR();
    MFMAQ32(0, 1, bF1);
    SCHED0(); BAR();
    // P3: Mt23 x Nt0; stage B-half0 of 2j+2 -> buf0 (B reads of buf0 done @P2)
    LOADA32(2, 0);
    STAGE(tB2, 1, 0, 0);
    BAR();
    MFMAQ32(2, 0, bF0);
    SCHED0(); BAR();
    // P4: Mt23 x Nt1; stage B-half1 of 2j+2; counted vmcnt for buf1 tile
    STAGE(tB2, 1, 1, 0);
    BAR();
    MFMAQ32(2, 1, bF1);
    if (j < NITH - 1) { WAITV(4); } else { WAITV(0); }
    SCHED0(); BAR();
    // P5: tile 2j+1 (buf1) Mt01 x Nt0; stage A-half0 of 2j+2 (A-buf0 reads done @P3)
    LOADA32(0, 1); LOADB32(bF0, 0, 1);
    STAGE(tB2, 0, 0, 0);
    BAR();
    MFMAQ32(0, 0, bF0);
    SCHED0(); BAR();
    // P6: Mt01 x Nt1; stage A-half1 of 2j+2
    LOADB32(bF1, 1, 1);
    STAGE(tB2, 0, 1, 0);
    BAR();
    MFMAQ32(0, 1, bF1);
    SCHED0(); BAR();
    // P7: Mt23 x Nt0; stage B-half0 of 2j+3 -> buf1 (B-buf1 reads done @P6)
    LOADA32(2, 1);
    STAGE(tB3, 1, 0, 1);
    BAR();
    MFMAQ32(2, 0, bF0);
    SCHED0(); BAR();
    // P8: Mt23 x Nt1; stage B-half1 of 2j+3; counted vmcnt for next buf0 tile
    STAGE(tB3, 1, 1, 1);
    BAR();
    MFMAQ32(2, 1, bF1);
    if (j < NITH - 1) { WAITV(4); }
    SCHED0(); BAR();
  }

  // 32x32 C/D layout (verified m74/m101): col = lane&31,
  // row = (reg&3) + 8*(reg>>2) + 4*(lane>>5), reg in [0,16).
  const size_t r0 = (size_t)bm * 256 + wm * 128 + 4 * kl;
  const int c0 = bn * 256 + wn * 64 + r31;
#pragma unroll
  for (int mt = 0; mt < 4; ++mt)
#pragma unroll
    for (int nt = 0; nt < 2; ++nt)
#pragma unroll
      for (int r = 0; r < 16; ++r) {
        const size_t row = r0 + mt * 32 + (r & 3) + 8 * (r >> 2);
        C[row * OUT_F + (c0 + nt * 32)] = acc[mt][nt][r];
      }
}

// Row LayerNorm over C0+C1+bias, written in place to C0.
__global__ __launch_bounds__(256) void ln_kernel(float* __restrict__ C,
                                                 const float* __restrict__ P,
                                                 const float* __restrict__ bias,
                                                 const float* __restrict__ gamma,
                                                 const float* __restrict__ beta) {
  const int row = blockIdx.x;
  const int tid = threadIdx.x;
  float4 v = *reinterpret_cast<const float4*>(C + (size_t)row * OUT_F + tid * 4);
  const float4 p = *reinterpret_cast<const float4*>(P + (size_t)row * OUT_F + tid * 4);
  const float4 bb = *reinterpret_cast<const float4*>(bias + tid * 4);
  v.x += p.x + bb.x; v.y += p.y + bb.y; v.z += p.z + bb.z; v.w += p.w + bb.w;
  float s = v.x + v.y + v.z + v.w;
  float q = v.x * v.x + v.y * v.y + v.z * v.z + v.w * v.w;
#pragma unroll
  for (int off = 32; off > 0; off >>= 1) {
    s += __shfl_down(s, off);
    q += __shfl_down(q, off);
  }
  __shared__ float red[8];
  const int wave = tid >> 6, lane = tid & 63;
  if (lane == 0) { red[wave] = s; red[4 + wave] = q; }
  __syncthreads();
  s = red[0] + red[1] + red[2] + red[3];
  q = red[4] + red[5] + red[6] + red[7];
  const float mu = s * (1.0f / OUT_F);
  const float var = q * (1.0f / OUT_F) - mu * mu;
  const float rs = rsqrtf(var + LN_EPS);
  const float4 g = *reinterpret_cast<const float4*>(gamma + tid * 4);
  const float4 be = *reinterpret_cast<const float4*>(beta + tid * 4);
  float4 o;
  o.x = g.x * (v.x - mu) * rs + be.x;
  o.y = g.y * (v.y - mu) * rs + be.y;
  o.z = g.z * (v.z - mu) * rs + be.z;
  o.w = g.w * (v.w - mu) * rs + be.w;
  *reinterpret_cast<float4*>(C + (size_t)row * OUT_F + tid * 4) = o;
}

extern "C" void kernel_launch(void* const* d_in, const int* in_sizes, int n_in,
                              void* d_out, int out_size, void* d_ws, size_t ws_size,
                              hipStream_t stream) {
  const float* x     = (const float*)d_in[0];
  const float* cp    = (const float*)d_in[1];
  const float* W     = (const float*)d_in[2];
  const float* bias  = (const float*)d_in[3];
  const float* gamma = (const float*)d_in[4];
  const float* beta  = (const float*)d_in[5];
  float* out = (float*)d_out;

  unsigned short* Bm = (unsigned short*)d_ws;
  const size_t bBytes = (size_t)OUT_F * KP * sizeof(unsigned short);   // 24 MiB
  size_t avail = ws_size > bBytes ? ws_size - bBytes : 0;
  // per-row: 24 KiB bf16 features + 4 KiB fp32 partial
  const size_t perRow = (size_t)KP * 2 + (size_t)OUT_F * 4;
  long long fit = (long long)(avail / perRow);
  int chunk;
  if (fit >= BATCH)     chunk = BATCH;   // 512 WGs = 2 full fill rounds
  else if (fit >= 8192) chunk = 8192;    // 256 WGs = exact full fill
  else                  chunk = (int)((fit / 256) * 256);
  if (chunk < 256) chunk = 256;

  unsigned short* Af = (unsigned short*)((char*)d_ws + bBytes);
  float* P = (float*)(Af + (size_t)chunk * KP);

  bgen<<<OUT_F, 256, 0, stream>>>(cp, W, Bm);
  for (int r0 = 0; r0 < BATCH; r0 += chunk) {
    const int rows = (BATCH - r0 < chunk) ? (BATCH - r0) : chunk;
    featgen<<<rows, 256, 0, stream>>>(x, Af, r0);
    const int nbm = rows / 256;
    gemm8p<<<nbm * 8, 512, 0, stream>>>(Af, Bm, out + (size_t)r0 * OUT_F, P, nbm);
    ln_kernel<<<rows, 256, 0, stream>>>(out + (size_t)r0 * OUT_F, P, bias, gamma, beta);
  }
}

// Round 6
// 442.328 us; speedup vs baseline: 1.1232x; 1.1232x over previous
//
#include <hip/hip_runtime.h>
#include <hip/hip_bf16.h>

#define BATCH   16384
#define IN_F    1024
#define OUT_F   1024
#define KCOLS   11
#define KPL     12          // 11 basis planes + 1 x-plane (for W)
#define KP      (KPL*IN_F)  // 12288
#define KHALF   (KP/2)      // 6144 per split-K block
#define NTKH    (KHALF/64)  // 96 K-tiles of 64 per half
#define NITH    (NTKH/2)    // 48 main-loop iterations (2 K-tiles each)
#define LN_EPS  1e-5f

typedef __attribute__((ext_vector_type(8))) short short8;
typedef __attribute__((ext_vector_type(4))) float f32x4;

static __device__ __forceinline__ unsigned short f2bf(float f) {
  __hip_bfloat16 h = __float2bfloat16(f);
  return *reinterpret_cast<unsigned short*>(&h);
}

// Cox-de Boor, faithful to the reference's in-place variant.
// All denominators are compile-time constants -> multiply by folded reciprocal.
__device__ __forceinline__ void bspline_basis(float x, float bas[KCOLS]) {
  const float s = 1.0f / 11.0f;
  float kn[12];
#pragma unroll
  for (int j = 0; j < 12; ++j) kn[j] = (float)j * s;
  kn[11] = 1.0f;
#pragma unroll
  for (int j = 0; j < 11; ++j)
    bas[j] = (x >= kn[j] && x < kn[j + 1]) ? 1.0f : 0.0f;
#pragma unroll
  for (int d = 1; d <= 3; ++d) {
#pragma unroll
    for (int j = 0; j < 11 - d; ++j) {
      const float r1 = 1.0f / (kn[j + d] - kn[j]);
      const float r2 = 1.0f / (kn[j + d + 1] - kn[j + 1]);
      float a = (x - kn[j]) * r1;
      float c = (kn[j + d + 1] - x) * r2;
      bas[j] = a * bas[j] + c * bas[j + 1];
    }
  }
}

// A[localRow][k*1024 + i] (bf16): 11 basis planes + x plane.
__global__ __launch_bounds__(256) void featgen(const float* __restrict__ X,
                                               unsigned short* __restrict__ A,
                                               int row0) {
  const int brow = blockIdx.x;
  const int i0 = threadIdx.x * 4;
  const float4 xv = *reinterpret_cast<const float4*>(X + (size_t)(row0 + brow) * IN_F + i0);
  float xs[4] = {xv.x, xv.y, xv.z, xv.w};
  float bas[4][KCOLS];
#pragma unroll
  for (int t = 0; t < 4; ++t) bspline_basis(xs[t], bas[t]);
  unsigned short* outp = A + (size_t)brow * KP + i0;
#pragma unroll
  for (int k = 0; k < KCOLS; ++k) {
    ushort4 u;
    u.x = f2bf(bas[0][k]); u.y = f2bf(bas[1][k]);
    u.z = f2bf(bas[2][k]); u.w = f2bf(bas[3][k]);
    *reinterpret_cast<ushort4*>(outp + (size_t)k * IN_F) = u;
  }
  ushort4 u;
  u.x = f2bf(xs[0]); u.y = f2bf(xs[1]); u.z = f2bf(xs[2]); u.w = f2bf(xs[3]);
  *reinterpret_cast<ushort4*>(outp + (size_t)KCOLS * IN_F) = u;
}

// Bmat[o][k*1024 + i] (bf16): cp planes + W plane.
__global__ __launch_bounds__(256) void bgen(const float* __restrict__ CP,
                                            const float* __restrict__ W,
                                            unsigned short* __restrict__ Bm) {
  const int o = blockIdx.x;
  const int i0 = threadIdx.x * 4;
  unsigned short* outp = Bm + (size_t)o * KP + i0;
#pragma unroll
  for (int k = 0; k < KCOLS; ++k) {
    ushort4 u;
    u.x = f2bf(CP[((size_t)o * IN_F + i0 + 0) * KCOLS + k]);
    u.y = f2bf(CP[((size_t)o * IN_F + i0 + 1) * KCOLS + k]);
    u.z = f2bf(CP[((size_t)o * IN_F + i0 + 2) * KCOLS + k]);
    u.w = f2bf(CP[((size_t)o * IN_F + i0 + 3) * KCOLS + k]);
    *reinterpret_cast<ushort4*>(outp + (size_t)k * IN_F) = u;
  }
  ushort4 u;
  u.x = f2bf(W[(size_t)o * IN_F + i0 + 0]);
  u.y = f2bf(W[(size_t)o * IN_F + i0 + 1]);
  u.z = f2bf(W[(size_t)o * IN_F + i0 + 2]);
  u.w = f2bf(W[(size_t)o * IN_F + i0 + 3]);
  *reinterpret_cast<ushort4*>(outp + (size_t)KCOLS * IN_F) = u;
}

// ---------------- 256x256 single-barrier-phase split-K GEMM (16x16x32) -------
// ks=0 blocks -> Cc, ks=1 blocks -> Cp. Grid = nbm*8; 8192 rows -> 256 WGs.
// 512 thr = 8 waves (2M x 4N); BK=64; LDS 128 KiB double-buffered.
// ONE barrier per phase (trailing). Safety: every STAGE(region) is >=1 barrier
// after that region's last ds_read; a wave's reads complete before it passes
// its trailing barrier (lgkmcnt precedes the consuming MFMA). Waves de-phase
// by <1 phase, so one wave's MFMA overlaps neighbors' LDS-read windows.

#define BAR()    __builtin_amdgcn_s_barrier()
#define SCHED0() __builtin_amdgcn_sched_barrier(0)
#define WAITV(N) asm volatile("s_waitcnt vmcnt(" #N ")" ::: "memory")

__global__ __launch_bounds__(512, 2) void gemm8p(const unsigned short* __restrict__ A,
                                                 const unsigned short* __restrict__ Bm,
                                                 float* __restrict__ Cc,
                                                 float* __restrict__ Cp, int nbm) {
  __shared__ unsigned short lds[2][2][2][128 * 64];  // [buf][A=0/B=1][half][...]
  const int tid  = (int)threadIdx.x;
  const int lane = tid & 63;
  const int w    = tid >> 6;
  const int wm   = w >> 2;       // 0..1
  const int wn   = w & 3;        // 0..3

  // XCD-aware bijective swizzle; per-XCD chunk = {4 bm} x {2 ks} x {4 bn}.
  const int nwg = nbm * 8;
  const int cpx = nwg >> 3;
  const int bid = (int)blockIdx.x;
  const int swz = (bid & 7) * cpx + (bid >> 3);
  const int bn = swz & 3;
  const int ks = (swz >> 2) & 1;
  const int bm = swz >> 3;
  const size_t koff = (size_t)ks * KHALF;
  float* __restrict__ C = ks ? Cp : Cc;

  // staging: one issue = 512 thr x 16 B = 64 rows x 64 cols.
  // Linear LDS dest; source col carries the inverse swizzle c ^ (row&7).
  const int srow = (w << 3) + (lane >> 3);            // 0..63 within one issue
  const int scol = ((lane & 7) ^ (lane >> 3)) << 3;   // element col, swizzled
  const unsigned short* aB = A  + (size_t)(bm * 256 + srow) * KP + koff + scol;
  const unsigned short* bB = Bm + (size_t)(bn * 256 + srow) * KP + koff + scol;

#define STAGE(T, AB, H, BUF)                                                          \
  do {                                                                                \
    if ((T) < NTKH) {                                                                 \
      const unsigned short* g_ = ((AB) ? bB : aB) + (size_t)(H) * 128 * KP + (size_t)(T) * 64; \
      unsigned short* l_ = &lds[BUF][AB][H][w * 512];                                 \
      __builtin_amdgcn_global_load_lds((const __attribute__((address_space(1))) void*)g_,       \
                                       (__attribute__((address_space(3))) void*)l_, 16, 0, 0);  \
      __builtin_amdgcn_global_load_lds((const __attribute__((address_space(1))) void*)(g_ + (size_t)64 * KP), \
                                       (__attribute__((address_space(3))) void*)(l_ + 4096), 16, 0, 0); \
    }                                                                                 \
  } while (0)

  // fragment reads (ds_read_b128, swizzled col)
  const int fr = lane & 15;
  const int g4 = lane >> 4;
  const int s7 = lane & 7;
  const int col0 = ((g4 ^ s7) << 3);        // kk=0 (elements)
  const int col1 = (((4 + g4) ^ s7) << 3);  // kk=1
  const unsigned short* aH[2] = {&lds[0][0][wm][0], &lds[1][0][wm][0]};
  const unsigned short* bH[2] = {&lds[0][1][wn >> 1][0], &lds[1][1][wn >> 1][0]};
  const int brow0 = (wn & 1) * 64;

  short8 aF[4][2], bF0[2][2], bF1[2][2];
  f32x4 acc[8][4] = {};

#define LOADA(MB, BUF)                                                         \
  do {                                                                         \
    _Pragma("unroll") for (int m_ = 0; m_ < 4; ++m_) {                         \
      const unsigned short* p_ = aH[BUF] + ((MB) + m_) * 1024 + fr * 64;       \
      aF[m_][0] = *reinterpret_cast<const short8*>(p_ + col0);                 \
      aF[m_][1] = *reinterpret_cast<const short8*>(p_ + col1);                 \
    }                                                                          \
  } while (0)

#define LOADB(DST, NB, BUF)                                                    \
  do {                                                                         \
    _Pragma("unroll") for (int n_ = 0; n_ < 2; ++n_) {                         \
      const unsigned short* p_ = bH[BUF] + (brow0 + ((NB) + n_) * 16 + fr) * 64; \
      DST[n_][0] = *reinterpret_cast<const short8*>(p_ + col0);                \
      DST[n_][1] = *reinterpret_cast<const short8*>(p_ + col1);                \
    }                                                                          \
  } while (0)

#define MFMAQ(MB, NB, BF)                                                      \
  do {                                                                         \
    __builtin_amdgcn_s_setprio(1);                                             \
    _Pragma("unroll") for (int m_ = 0; m_ < 4; ++m_)                           \
    _Pragma("unroll") for (int n_ = 0; n_ < 2; ++n_)                           \
    _Pragma("unroll") for (int kk_ = 0; kk_ < 2; ++kk_)                        \
      acc[(MB) + m_][(NB) + n_] = __builtin_amdgcn_mfma_f32_16x16x32_bf16(     \
          aF[m_][kk_], BF[n_][kk_], acc[(MB) + m_][(NB) + n_], 0, 0, 0);       \
    __builtin_amdgcn_s_setprio(0);                                             \
  } while (0)

  // prologue: tile0 (B0,B1,A0,A1) + tile1 (B0,B1); drain to 4 outstanding.
  STAGE(0, 1, 0, 0); STAGE(0, 1, 1, 0);
  STAGE(0, 0, 0, 0); STAGE(0, 0, 1, 0);
  STAGE(1, 1, 0, 1); STAGE(1, 1, 1, 1);
  WAITV(4);
  BAR();

#pragma unroll 1
  for (int j = 0; j < NITH; ++j) {
    const int tA = 2 * j + 1, tB2 = 2 * j + 2, tB3 = 2 * j + 3;
    // P1: quad(m0-3,n0-1) of tile 2j (buf0); stage A-half0 of tile 2j+1 -> buf1
    //     (buf1-A last read @prev P7; >=2 barriers ago)
    LOADA(0, 0); LOADB(bF0, 0, 0);
    STAGE(tA, 0, 0, 1);
    MFMAQ(0, 0, bF0);
    SCHED0(); BAR();
    // P2: quad(m0-3,n2-3); stage A-half1 of 2j+1
    LOADB(bF1, 2, 0);
    STAGE(tA, 0, 1, 1);
    MFMAQ(0, 2, bF1);
    SCHED0(); BAR();
    // P3: quad(m4-7,n0-1); stage B-half0 of 2j+2 -> buf0 (B-buf0 reads done @P2 + BAR)
    LOADA(4, 0);
    STAGE(tB2, 1, 0, 0);
    MFMAQ(4, 0, bF0);
    SCHED0(); BAR();
    // P4: quad(m4-7,n2-3); stage B-half1 of 2j+2; counted vmcnt for buf1 tile
    STAGE(tB2, 1, 1, 0);
    MFMAQ(4, 2, bF1);
    if (j < NITH - 1) { WAITV(4); } else { WAITV(0); }
    SCHED0(); BAR();
    // P5: tile 2j+1 (buf1) quad(m0-3,n0-1); stage A-half0 of 2j+2 (A-buf0 reads done @P3 + BAR)
    LOADA(0, 1); LOADB(bF0, 0, 1);
    STAGE(tB2, 0, 0, 0);
    MFMAQ(0, 0, bF0);
    SCHED0(); BAR();
    // P6: quad(m0-3,n2-3); stage A-half1 of 2j+2
    LOADB(bF1, 2, 1);
    STAGE(tB2, 0, 1, 0);
    MFMAQ(0, 2, bF1);
    SCHED0(); BAR();
    // P7: quad(m4-7,n0-1); stage B-half0 of 2j+3 -> buf1 (B-buf1 reads done @P6 + BAR)
    LOADA(4, 1);
    STAGE(tB3, 1, 0, 1);
    MFMAQ(4, 0, bF0);
    SCHED0(); BAR();
    // P8: quad(m4-7,n2-3); stage B-half1 of 2j+3; counted vmcnt for next buf0 tile
    STAGE(tB3, 1, 1, 1);
    MFMAQ(4, 2, bF1);
    if (j < NITH - 1) { WAITV(4); }
    SCHED0(); BAR();
  }

  // C/D layout (verified m89/m91): col = lane&15, row = (lane>>4)*4 + reg
  const size_t r0 = (size_t)bm * 256 + wm * 128 + (lane >> 4) * 4;
  const int c0 = bn * 256 + wn * 64 + fr;
#pragma unroll
  for (int m = 0; m < 8; ++m)
#pragma unroll
    for (int n = 0; n < 4; ++n)
#pragma unroll
      for (int r = 0; r < 4; ++r)
        C[(r0 + m * 16 + r) * OUT_F + (c0 + n * 16)] = acc[m][n][r];
}

// Row LayerNorm over C0+C1+bias, written in place to C0.
__global__ __launch_bounds__(256) void ln_kernel(float* __restrict__ C,
                                                 const float* __restrict__ P,
                                                 const float* __restrict__ bias,
                                                 const float* __restrict__ gamma,
                                                 const float* __restrict__ beta) {
  const int row = blockIdx.x;
  const int tid = threadIdx.x;
  float4 v = *reinterpret_cast<const float4*>(C + (size_t)row * OUT_F + tid * 4);
  const float4 p = *reinterpret_cast<const float4*>(P + (size_t)row * OUT_F + tid * 4);
  const float4 bb = *reinterpret_cast<const float4*>(bias + tid * 4);
  v.x += p.x + bb.x; v.y += p.y + bb.y; v.z += p.z + bb.z; v.w += p.w + bb.w;
  float s = v.x + v.y + v.z + v.w;
  float q = v.x * v.x + v.y * v.y + v.z * v.z + v.w * v.w;
#pragma unroll
  for (int off = 32; off > 0; off >>= 1) {
    s += __shfl_down(s, off);
    q += __shfl_down(q, off);
  }
  __shared__ float red[8];
  const int wave = tid >> 6, lane = tid & 63;
  if (lane == 0) { red[wave] = s; red[4 + wave] = q; }
  __syncthreads();
  s = red[0] + red[1] + red[2] + red[3];
  q = red[4] + red[5] + red[6] + red[7];
  const float mu = s * (1.0f / OUT_F);
  const float var = q * (1.0f / OUT_F) - mu * mu;
  const float rs = rsqrtf(var + LN_EPS);
  const float4 g = *reinterpret_cast<const float4*>(gamma + tid * 4);
  const float4 be = *reinterpret_cast<const float4*>(beta + tid * 4);
  float4 o;
  o.x = g.x * (v.x - mu) * rs + be.x;
  o.y = g.y * (v.y - mu) * rs + be.y;
  o.z = g.z * (v.z - mu) * rs + be.z;
  o.w = g.w * (v.w - mu) * rs + be.w;
  *reinterpret_cast<float4*>(C + (size_t)row * OUT_F + tid * 4) = o;
}

extern "C" void kernel_launch(void* const* d_in, const int* in_sizes, int n_in,
                              void* d_out, int out_size, void* d_ws, size_t ws_size,
                              hipStream_t stream) {
  const float* x     = (const float*)d_in[0];
  const float* cp    = (const float*)d_in[1];
  const float* W     = (const float*)d_in[2];
  const float* bias  = (const float*)d_in[3];
  const float* gamma = (const float*)d_in[4];
  const float* beta  = (const float*)d_in[5];
  float* out = (float*)d_out;

  unsigned short* Bm = (unsigned short*)d_ws;
  const size_t bBytes = (size_t)OUT_F * KP * sizeof(unsigned short);   // 24 MiB
  size_t avail = ws_size > bBytes ? ws_size - bBytes : 0;
  // per-row: 24 KiB bf16 features + 4 KiB fp32 partial
  const size_t perRow = (size_t)KP * 2 + (size_t)OUT_F * 4;
  long long fit = (long long)(avail / perRow);
  int chunk;
  if (fit >= BATCH)     chunk = BATCH;   // 512 WGs = 2 full fill rounds
  else if (fit >= 8192) chunk = 8192;    // 256 WGs = exact full fill
  else                  chunk = (int)((fit / 256) * 256);
  if (chunk < 256) chunk = 256;

  unsigned short* Af = (unsigned short*)((char*)d_ws + bBytes);
  float* P = (float*)(Af + (size_t)chunk * KP);

  bgen<<<OUT_F, 256, 0, stream>>>(cp, W, Bm);
  for (int r0 = 0; r0 < BATCH; r0 += chunk) {
    const int rows = (BATCH - r0 < chunk) ? (BATCH - r0) : chunk;
    featgen<<<rows, 256, 0, stream>>>(x, Af, r0);
    const int nbm = rows / 256;
    gemm8p<<<nbm * 8, 512, 0, stream>>>(Af, Bm, out + (size_t)r0 * OUT_F, P, nbm);
    ln_kernel<<<rows, 256, 0, stream>>>(out + (size_t)r0 * OUT_F, P, bias, gamma, beta);
  }
}